// Round 2
// baseline (484.321 us; speedup 1.0000x reference)
//
#include <hip/hip_runtime.h>
#include <hip/hip_cooperative_groups.h>

namespace cg = cooperative_groups;

#define N_NODES 100000
#define N_EDGES 300000
#define DIM     128
#define NBINS   (2 * N_NODES)        // bin = dst*2 + rel
#define CNT_STRIDE 8                 // 32B per bin (atomic line spreading)
#define SLOT_CAP 24                  // Poisson(3): P(any deg>=24) ~ 5e-9; passed R1
#define ROW_TILES (N_NODES / 16)     // 6250 (16 rows per tile, exact)
#define UNR 6                        // batched gathers per node (covers 98.5% of edges)

typedef __attribute__((ext_vector_type(8))) short bfrag;            // 8 bf16
typedef __attribute__((ext_vector_type(4))) float f32x4;
typedef __attribute__((ext_vector_type(4))) unsigned short u16x4;
typedef __attribute__((ext_vector_type(2))) unsigned int   u32x2;

__device__ __forceinline__ unsigned short f2bf(float f) {
  unsigned int u = __float_as_uint(f);
  u += 0x7FFFu + ((u >> 16) & 1u);    // round-to-nearest-even
  return (unsigned short)(u >> 16);
}
__device__ __forceinline__ float bflo(unsigned int u) { return __uint_as_float(u << 16); }
__device__ __forceinline__ float bfhi(unsigned int u) { return __uint_as_float(u & 0xffff0000u); }

// ---------------------------------------------------------------------------
// Phase pieces as __device__ functions, shared by the cooperative mega-kernel
// and the (insurance) classic 3-kernel fallback path.
// ---------------------------------------------------------------------------
__device__ __forceinline__ void do_zero(int* counts, int start, int stride) {
  for (int i = start; i < NBINS * CNT_STRIDE / 4; i += stride)
    ((int4*)counts)[i] = make_int4(0, 0, 0, 0);
}

// W (fp32 [k][c]) -> LDS bf16 Wt[c][k], XOR-swizzled: byte ^= ((c&7)<<4).
// B-frag reads (16B at 256B row stride) then hit 8 distinct 16B slots per
// 8 lanes -> 2-way bank aliasing = free (m136).
__device__ __forceinline__ void do_wt_lds(unsigned short* WtS, const float* W, int tid) {
  for (int e = tid; e < DIM * DIM; e += 256) {
    int k = e >> 7, c = e & 127;
    int byte = c * 256 + k * 2;
    int swz = byte ^ ((c & 7) << 4);
    WtS[swz >> 1] = f2bf(W[e]);
  }
}

// Edge binning. ALGEBRA: dst-side attention term is constant per softmax
// segment and cancels in alpha; only exp(sS[src]) matters.
__device__ __forceinline__ void do_bin(const int* __restrict__ src,
                                       const int* __restrict__ dst,
                                       int* __restrict__ counts, int* __restrict__ slots,
                                       int start, int stride) {
  for (int e = start; e < N_EDGES; e += stride) {
    int d0 = __builtin_nontemporal_load(&dst[e]);
    int d1 = __builtin_nontemporal_load(&dst[e + N_EDGES]);
    int s0 = __builtin_nontemporal_load(&src[e]);
    int s1 = __builtin_nontemporal_load(&src[e + N_EDGES]);
    int p0 = atomicAdd(&counts[(size_t)(d0 * 2 + 0) * CNT_STRIDE], 1);
    int p1 = atomicAdd(&counts[(size_t)(d1 * 2 + 1) * CNT_STRIDE], 1);
    if (p0 < SLOT_CAP)
      __builtin_nontemporal_store(s0, &slots[(size_t)(d0 * 2 + 0) * SLOT_CAP + p0]);
    if (p1 < SLOT_CAP)
      __builtin_nontemporal_store(s1, &slots[(size_t)(d1 * 2 + 1) * SLOT_CAP + p1]);
  }
}

// Scores + x->bf16 conversion. 16 rows per block-iteration; thread t of a
// 16-lane group owns floats [4t,4t+4) and [64+4t,64+4t+4) of its row:
// 2 independent float4 loads/thread, fully coalesced; 4-step shfl reduce.
__device__ __forceinline__ void do_scores(const float* __restrict__ x,
                                          const float* __restrict__ attn_w,
                                          float* __restrict__ pexp,
                                          unsigned short* __restrict__ x_bf,
                                          int tid, int bstart, int bstride) {
  int t    = tid & 15;
  int rsub = tid >> 4;                                   // row within 16-row tile
  const f32x4* A0 = (const f32x4*)attn_w;                // rel0 src half
  const f32x4* A1 = (const f32x4*)(attn_w + 2 * DIM);    // rel1 src half
  f32x4 a00 = A0[t], a01 = A0[t + 16];
  f32x4 a10 = A1[t], a11 = A1[t + 16];
  for (int tb = bstart; tb < ROW_TILES; tb += bstride) {
    int row = tb * 16 + rsub;
    const f32x4* xr = (const f32x4*)(x + (size_t)row * DIM);
    f32x4 v0 = __builtin_nontemporal_load(xr + t);       // read-once: keep L2 clean
    f32x4 v1 = __builtin_nontemporal_load(xr + t + 16);
    u16x4 b0, b1;
    b0.x = f2bf(v0.x); b0.y = f2bf(v0.y); b0.z = f2bf(v0.z); b0.w = f2bf(v0.w);
    b1.x = f2bf(v1.x); b1.y = f2bf(v1.y); b1.z = f2bf(v1.z); b1.w = f2bf(v1.w);
    u16x4* xb = (u16x4*)(x_bf + (size_t)row * DIM);
    xb[t] = b0; xb[t + 16] = b1;
    float p0 = v0.x*a00.x + v0.y*a00.y + v0.z*a00.z + v0.w*a00.w
             + v1.x*a01.x + v1.y*a01.y + v1.z*a01.z + v1.w*a01.w;
    float p1 = v0.x*a10.x + v0.y*a10.y + v0.z*a10.z + v0.w*a10.w
             + v1.x*a11.x + v1.y*a11.y + v1.z*a11.z + v1.w*a11.w;
    #pragma unroll
    for (int off = 8; off > 0; off >>= 1) {   // xor of bits 0..3: stays in 16-group
      p0 += __shfl_xor(p0, off, 64);
      p1 += __shfl_xor(p1, off, 64);
    }
    if (t == 0) {
      pexp[row]           = __expf(p0);
      pexp[N_NODES + row] = __expf(p1);
    }
  }
}

// One 16-row tile: MFMA GEMM (x@W + bias) into LDS, then attention aggregate
// with BATCHED gathers: issue up to UNR*4 = 24 independent row-gathers per
// wave before any FMA (was ~1-2 in flight -> the 2 TB/s plateau).
__device__ __forceinline__ void do_tile(const unsigned short* WtS, float (*gtile)[DIM],
    const int* __restrict__ slots, const int* __restrict__ counts,
    const float* __restrict__ pexp, const unsigned short* __restrict__ x_bf,
    const float* __restrict__ bias, float* __restrict__ out, int tid, int tb) {
  int r0 = tb * 16;
  int w  = tid >> 6;
  int wl = tid & 63;
  {
    // ---- GEMM quarter: wave w owns column-tiles {2w,2w+1}; C/D layout
    // col = ct*16 + (lane&15), row = (lane>>4)*4 + rr. Bias in acc init.
    int n = wl & 15, q = wl >> 4;
    const unsigned short* xrow = x_bf + (size_t)(r0 + n) * DIM;
    f32x4 acc[2];
    #pragma unroll
    for (int c = 0; c < 2; c++) {
      float bv = bias[(2 * w + c) * 16 + n];
      acc[c] = (f32x4){bv, bv, bv, bv};
    }
    #pragma unroll
    for (int kc = 0; kc < 4; kc++) {
      int k0 = kc * 32 + q * 8;
      bfrag a = *((const bfrag*)(xrow + k0));
      #pragma unroll
      for (int c = 0; c < 2; c++) {
        int cc   = (2 * w + c) * 16 + n;
        int byte = cc * 256 + k0 * 2;
        const bfrag* bp = (const bfrag*)((const char*)WtS + (byte ^ ((cc & 7) << 4)));
        acc[c] = __builtin_amdgcn_mfma_f32_16x16x32_bf16(a, *bp, acc[c], 0, 0, 0);
      }
    }
    #pragma unroll
    for (int c = 0; c < 2; c++)
      #pragma unroll
      for (int rr = 0; rr < 4; rr++)
        gtile[q * 4 + rr][(2 * w + c) * 16 + n] = acc[c][rr];
  }
  __syncthreads();
  // ---- aggregation: half-wave rrel handles relation rrel; 4 nodes/wave.
  int rrel  = wl >> 5;
  int l     = wl & 31;
  int nbase = r0 + w * 4;
  int cnt[4]; int sj[4]; float pj[4]; float dinv[4];
  #pragma unroll
  for (int nn = 0; nn < 4; nn++) {
    int c = counts[(size_t)((nbase + nn) * 2 + rrel) * CNT_STRIDE];
    cnt[nn] = (c > SLOT_CAP) ? SLOT_CAP : c;
  }
  #pragma unroll
  for (int nn = 0; nn < 4; nn++)
    sj[nn] = (l < cnt[nn]) ? slots[(size_t)((nbase + nn) * 2 + rrel) * SLOT_CAP + l] : 0;
  #pragma unroll
  for (int nn = 0; nn < 4; nn++)
    pj[nn] = (l < cnt[nn]) ? pexp[rrel * N_NODES + sj[nn]] : 0.f;
  #pragma unroll
  for (int nn = 0; nn < 4; nn++) {
    float d = pj[nn];
    #pragma unroll
    for (int off = 16; off > 0; off >>= 1) d += __shfl_xor(d, off, 64);  // in-half
    dinv[nn] = (cnt[nn] > 0) ? 1.f / d : 0.f;
  }
  // Batch-ISSUE phase: up to 24 independent gathers in flight, no waits between.
  u32x2 g[4][UNR];
  #pragma unroll
  for (int nn = 0; nn < 4; nn++) {
    #pragma unroll
    for (int u = 0; u < UNR; u++) {
      int s = __shfl(sj[nn], u, 32);
      if (u < cnt[nn])
        g[nn][u] = ((const u32x2*)(x_bf + (size_t)s * DIM))[l];
    }
  }
  // FMA phase.
  f32x4 accr[4];
  #pragma unroll
  for (int nn = 0; nn < 4; nn++) accr[nn] = (f32x4){0.f, 0.f, 0.f, 0.f};
  #pragma unroll
  for (int nn = 0; nn < 4; nn++) {
    #pragma unroll
    for (int u = 0; u < UNR; u++) {
      float qv = __shfl(pj[nn], u, 32);
      if (u < cnt[nn]) {
        u32x2 gv = g[nn][u];
        accr[nn].x += qv * bflo(gv.x);
        accr[nn].y += qv * bfhi(gv.x);
        accr[nn].z += qv * bflo(gv.y);
        accr[nn].w += qv * bfhi(gv.y);
      }
    }
  }
  // Serial tail for cnt > UNR (~1.5% of edges).
  #pragma unroll
  for (int nn = 0; nn < 4; nn++) {
    for (int j = UNR; j < cnt[nn]; j++) {
      int   s  = __shfl(sj[nn], j, 32);
      float qv = __shfl(pj[nn], j, 32);
      u32x2 gv = ((const u32x2*)(x_bf + (size_t)s * DIM))[l];
      accr[nn].x += qv * bflo(gv.x); accr[nn].y += qv * bfhi(gv.x);
      accr[nn].z += qv * bflo(gv.y); accr[nn].w += qv * bfhi(gv.y);
    }
  }
  #pragma unroll
  for (int nn = 0; nn < 4; nn++) {
    f32x4 agg;
    agg.x = accr[nn].x * dinv[nn];
    agg.y = accr[nn].y * dinv[nn];
    agg.z = accr[nn].z * dinv[nn];
    agg.w = accr[nn].w * dinv[nn];
    agg.x += __shfl_xor(agg.x, 32, 64);   // combine rel0 + rel1 halves
    agg.y += __shfl_xor(agg.y, 32, 64);
    agg.z += __shfl_xor(agg.z, 32, 64);
    agg.w += __shfl_xor(agg.w, 32, 64);
    if (wl < 32) {
      const float* gr = &gtile[w * 4 + nn][4 * wl];
      f32x4 o;
      o.x = gr[0] + agg.x; o.y = gr[1] + agg.y;
      o.z = gr[2] + agg.z; o.w = gr[3] + agg.w;
      __builtin_nontemporal_store(o, (f32x4*)(out + (size_t)(nbase + nn) * DIM) + wl);
    }
  }
  __syncthreads();   // gtile reused next iteration
}

// ---------------------------------------------------------------------------
// Cooperative mega-kernel: 1 dispatch, 2 grid syncs.
// ---------------------------------------------------------------------------
__global__ __launch_bounds__(256, 4) void mega_kernel(
    const float* __restrict__ x, const float* __restrict__ attn_w,
    const float* __restrict__ W, const float* __restrict__ bias,
    const int* __restrict__ src, const int* __restrict__ dst,
    float* __restrict__ pexp, int* __restrict__ counts, int* __restrict__ slots,
    unsigned short* __restrict__ x_bf, float* __restrict__ out) {
  __shared__ unsigned short WtS[DIM * DIM];   // 32 KB
  __shared__ float gtile[16][DIM];            // 8 KB  (total 40960B -> 4 blocks/CU)
  int tid  = threadIdx.x;
  int gtid = blockIdx.x * 256 + tid;
  int gsz  = gridDim.x * 256;
  do_wt_lds(WtS, W, tid);                     // independent; overlaps zeroing
  do_zero(counts, gtid, gsz);
  cg::this_grid().sync();
  do_bin(src, dst, counts, slots, gtid, gsz); // atomics issued early...
  do_scores(x, attn_w, pexp, x_bf, tid, blockIdx.x, gridDim.x);  // ...hide under BW work
  cg::this_grid().sync();
  for (int tb = blockIdx.x; tb < ROW_TILES; tb += gridDim.x)
    do_tile(WtS, gtile, slots, counts, pexp, x_bf, bias, out, tid, tb);
}

// ---------------------------------------------------------------------------
// Fallback (classic 3-dispatch) path in case cooperative launch is rejected.
// ---------------------------------------------------------------------------
#define FB_BIN_BLOCKS ((N_EDGES + 255) / 256)   // 1172

__global__ __launch_bounds__(256) void fb_k0(int* __restrict__ counts) {
  do_zero(counts, blockIdx.x * 256 + threadIdx.x, gridDim.x * 256);
}
__global__ __launch_bounds__(256) void fb_k1(
    const float* __restrict__ x, const float* __restrict__ attn_w,
    const int* __restrict__ src, const int* __restrict__ dst,
    float* __restrict__ pexp, int* __restrict__ counts, int* __restrict__ slots,
    unsigned short* __restrict__ x_bf) {
  if (blockIdx.x < FB_BIN_BLOCKS) {
    do_bin(src, dst, counts, slots, blockIdx.x * 256 + threadIdx.x, FB_BIN_BLOCKS * 256);
    return;
  }
  do_scores(x, attn_w, pexp, x_bf, threadIdx.x, blockIdx.x - FB_BIN_BLOCKS, ROW_TILES);
}
__global__ __launch_bounds__(256) void fb_k2(
    const float* __restrict__ W, const int* __restrict__ slots,
    const int* __restrict__ counts, const float* __restrict__ pexp,
    const unsigned short* __restrict__ x_bf, const float* __restrict__ bias,
    float* __restrict__ out) {
  __shared__ unsigned short WtS[DIM * DIM];
  __shared__ float gtile[16][DIM];
  do_wt_lds(WtS, W, threadIdx.x);
  __syncthreads();
  do_tile(WtS, gtile, slots, counts, pexp, x_bf, bias, out, threadIdx.x, blockIdx.x);
}

extern "C" void kernel_launch(void* const* d_in, const int* in_sizes, int n_in,
                              void* d_out, int out_size, void* d_ws, size_t ws_size,
                              hipStream_t stream) {
  const float* x      = (const float*)d_in[0];
  const float* attn_w = (const float*)d_in[1];
  const float* loop_w = (const float*)d_in[2];
  const float* h_bias = (const float*)d_in[3];
  const int*   src    = (const int*)d_in[4];
  const int*   dst    = (const int*)d_in[5];
  float*       out    = (float*)d_out;

  // ws: pexp[2N] f (0.8MB) | counts[2N*8] i (6.4MB) | slots[2N*24] i (19.2MB) |
  //     x_bf[N*128] u16 (25.6MB)  = 52.0MB total (ws_size >= 54.4MB confirmed)
  float*          pexp   = (float*)d_ws;
  int*            counts = (int*)(pexp + NBINS);
  int*            slots  = counts + (size_t)NBINS * CNT_STRIDE;
  unsigned short* x_bf   = (unsigned short*)(slots + (size_t)NBINS * SLOT_CAP);

  static int coop_blocks = -2;   // -2 untested, -1 fallback, >0 coop grid size
  if (coop_blocks == -2) {
    int bpc = 0;
    hipError_t qe = hipOccupancyMaxActiveBlocksPerMultiprocessor(
        &bpc, (const void*)mega_kernel, 256, 0);
    coop_blocks = (qe == hipSuccess && bpc >= 1) ? bpc * 256 : -1;
  }
  if (coop_blocks > 0) {
    void* args[] = {(void*)&x, (void*)&attn_w, (void*)&loop_w, (void*)&h_bias,
                    (void*)&src, (void*)&dst, (void*)&pexp, (void*)&counts,
                    (void*)&slots, (void*)&x_bf, (void*)&out};
    hipError_t le = hipLaunchCooperativeKernel((const void*)mega_kernel,
        dim3(coop_blocks), dim3(256), args, 0, stream);
    if (le == hipSuccess) return;
    coop_blocks = -1;            // rejected (e.g., by capture) -> classic path
  }
  fb_k0<<<(NBINS * CNT_STRIDE / 4 + 255) / 256, 256, 0, stream>>>(counts);
  fb_k1<<<FB_BIN_BLOCKS + ROW_TILES, 256, 0, stream>>>(
      x, attn_w, src, dst, pexp, counts, slots, x_bf);
  fb_k2<<<ROW_TILES, 256, 0, stream>>>(loop_w, slots, counts, pexp, x_bf, h_bias, out);
}

// Round 3
// 415.097 us; speedup vs baseline: 1.1668x; 1.1668x over previous
//
#include <hip/hip_runtime.h>
#include <hip/hip_cooperative_groups.h>

namespace cg = cooperative_groups;

#define N_NODES 100000
#define N_EDGES 300000
#define DIM     128
#define NBINS   (2 * N_NODES)        // bin = dst*2 + rel
#define CNT_STRIDE 8                 // 32B per bin (atomic line spreading)
#define SLOT_CAP 24                  // Poisson(3): P(any deg>=24) ~ 5e-9; passed R1/R2
#define ROW_TILES (N_NODES / 16)     // 6250 (16 rows per tile, exact)
#define GDIM (DIM + 4)               // gtile pad: kills 4-way bank conflict on C-writes

typedef __attribute__((ext_vector_type(8))) short bfrag;            // 8 bf16
typedef __attribute__((ext_vector_type(4))) float f32x4;
typedef __attribute__((ext_vector_type(2))) float f32x2;
typedef __attribute__((ext_vector_type(2))) unsigned int   u32x2;

__device__ __forceinline__ unsigned short f2bf(float f) {
  unsigned int u = __float_as_uint(f);
  u += 0x7FFFu + ((u >> 16) & 1u);    // round-to-nearest-even
  return (unsigned short)(u >> 16);
}
__device__ __forceinline__ float bflo(unsigned int u) { return __uint_as_float(u << 16); }
__device__ __forceinline__ float bfhi(unsigned int u) { return __uint_as_float(u & 0xffff0000u); }

// ---------------------------------------------------------------------------
// Phase pieces (shared by cooperative mega-kernel and classic fallback).
// All are the round-1 implementations (known-good perf, 36-56 VGPR) with two
// surgical fixes: de-predicated slot reads and padded gtile.
// ---------------------------------------------------------------------------
__device__ __forceinline__ void do_zero(int* counts, int start, int stride) {
  for (int i = start; i < NBINS * CNT_STRIDE / 4; i += stride)
    ((int4*)counts)[i] = make_int4(0, 0, 0, 0);
}

// W (fp32 [k][c]) -> GLOBAL bf16 Wt[c][k]. Global (not LDS): B-frag loads hit
// L2 (32KB, resident) and avoid the 8-way LDS conflict of the R2 swizzle.
__device__ __forceinline__ void do_wtconv(unsigned short* Wt, const float* W,
                                          int start, int stride) {
  for (int e = start; e < DIM * DIM; e += stride) {
    int k = e >> 7, c = e & 127;
    Wt[c * DIM + k] = f2bf(W[e]);
  }
}

// Edge binning. ALGEBRA: dst-side attention term is constant per softmax
// segment and cancels in alpha; only exp(sS[src]) matters.
__device__ __forceinline__ void do_bin(const int* __restrict__ src,
                                       const int* __restrict__ dst,
                                       int* __restrict__ counts, int* __restrict__ slots,
                                       int start, int stride) {
  for (int e = start; e < N_EDGES; e += stride) {
    int d0 = __builtin_nontemporal_load(&dst[e]);
    int d1 = __builtin_nontemporal_load(&dst[e + N_EDGES]);
    int s0 = __builtin_nontemporal_load(&src[e]);
    int s1 = __builtin_nontemporal_load(&src[e + N_EDGES]);
    int p0 = atomicAdd(&counts[(size_t)(d0 * 2 + 0) * CNT_STRIDE], 1);
    int p1 = atomicAdd(&counts[(size_t)(d1 * 2 + 1) * CNT_STRIDE], 1);
    if (p0 < SLOT_CAP)
      __builtin_nontemporal_store(s0, &slots[(size_t)(d0 * 2 + 0) * SLOT_CAP + p0]);
    if (p1 < SLOT_CAP)
      __builtin_nontemporal_store(s1, &slots[(size_t)(d1 * 2 + 1) * SLOT_CAP + p1]);
  }
}

// Scores + x->bf16: one wave per node (round-1 form). 64 lanes x float2 =
// one fully-coalesced 512B row read; NT load keeps L3 for x_bf gathers.
__device__ __forceinline__ void do_scores(const float* __restrict__ x,
                                          const float* __restrict__ attn_w,
                                          float* __restrict__ pexp,
                                          unsigned short* __restrict__ x_bf,
                                          int wave, int nwaves, int lane) {
  f32x2 a0 = ((const f32x2*)(attn_w +   0))[lane];   // rel0 src-half
  f32x2 a1 = ((const f32x2*)(attn_w + 256))[lane];   // rel1 src-half
  for (int n = wave; n < N_NODES; n += nwaves) {
    f32x2 v = __builtin_nontemporal_load(((const f32x2*)(x + (size_t)n * DIM)) + lane);
    ushort2 bv; bv.x = f2bf(v.x); bv.y = f2bf(v.y);
    ((ushort2*)(x_bf + (size_t)n * DIM))[lane] = bv;
    float p0 = v.x * a0.x + v.y * a0.y;
    float p1 = v.x * a1.x + v.y * a1.y;
    #pragma unroll
    for (int off = 32; off > 0; off >>= 1) {
      p0 += __shfl_down(p0, off, 64);
      p1 += __shfl_down(p1, off, 64);
    }
    if (lane == 0) {
      pexp[n]           = __expf(p0);
      pexp[N_NODES + n] = __expf(p1);
    }
  }
}

// One 16-row tile: MFMA GEMM (x@W + bias, B from global Wt) into padded LDS,
// then attention aggregate (round-1 loop: 4-deep gather batches, ~36 VGPR).
// Fix vs R1: counts and slots loads issue CONCURRENTLY (slot read is
// unconditional -- array fully allocated -- masked after the fact), removing
// one ~500-cycle serial latency per 4-node group.
__device__ __forceinline__ void do_tile(float (*gtile)[GDIM],
    const int* __restrict__ slots, const int* __restrict__ counts,
    const float* __restrict__ pexp, const unsigned short* __restrict__ x_bf,
    const unsigned short* __restrict__ Wt, const float* __restrict__ bias,
    float* __restrict__ out, int tid, int tb) {
  int r0 = tb * 16;
  int w  = tid >> 6;
  int wl = tid & 63;
  {
    // GEMM quarter: wave w owns column-tiles {2w,2w+1}; C/D layout
    // col = ct*16 + (lane&15), row = (lane>>4)*4 + rr. Bias in acc init.
    int n = wl & 15, q = wl >> 4;
    const unsigned short* xrow = x_bf + (size_t)(r0 + n) * DIM;
    f32x4 acc[2];
    #pragma unroll
    for (int c = 0; c < 2; c++) {
      float bv = bias[(2 * w + c) * 16 + n];
      acc[c] = (f32x4){bv, bv, bv, bv};
    }
    #pragma unroll
    for (int kc = 0; kc < 4; kc++) {
      int k0 = kc * 32 + q * 8;
      bfrag a = *((const bfrag*)(xrow + k0));
      #pragma unroll
      for (int c = 0; c < 2; c++) {
        bfrag b = *((const bfrag*)(Wt + (size_t)((2 * w + c) * 16 + n) * DIM + k0));
        acc[c] = __builtin_amdgcn_mfma_f32_16x16x32_bf16(a, b, acc[c], 0, 0, 0);
      }
    }
    #pragma unroll
    for (int c = 0; c < 2; c++)
      #pragma unroll
      for (int rr = 0; rr < 4; rr++)
        gtile[q * 4 + rr][(2 * w + c) * 16 + n] = acc[c][rr];
  }
  __syncthreads();
  // Aggregation: half-wave rrel handles relation rrel; 4 nodes/wave.
  int rrel  = wl >> 5;
  int l     = wl & 31;
  int nbase = r0 + w * 4;
  int craw[4], sraw[4];
  #pragma unroll
  for (int nn = 0; nn < 4; nn++)
    craw[nn] = counts[(size_t)((nbase + nn) * 2 + rrel) * CNT_STRIDE];
  #pragma unroll
  for (int nn = 0; nn < 4; nn++)   // independent of craw: 8 loads in flight
    sraw[nn] = slots[(size_t)((nbase + nn) * 2 + rrel) * SLOT_CAP + l];
  int cnt[4]; int sj[4]; float pj[4]; float dinv[4];
  #pragma unroll
  for (int nn = 0; nn < 4; nn++) {
    cnt[nn] = (craw[nn] > SLOT_CAP) ? SLOT_CAP : craw[nn];
    sj[nn]  = (l < cnt[nn]) ? sraw[nn] : 0;    // mask garbage before indexing
  }
  #pragma unroll
  for (int nn = 0; nn < 4; nn++)
    pj[nn] = (l < cnt[nn]) ? pexp[rrel * N_NODES + sj[nn]] : 0.f;
  #pragma unroll
  for (int nn = 0; nn < 4; nn++) {
    float d = pj[nn];
    #pragma unroll
    for (int off = 16; off > 0; off >>= 1) d += __shfl_xor(d, off, 64);  // in-half
    dinv[nn] = (cnt[nn] > 0) ? 1.f / d : 0.f;
  }
  #pragma unroll
  for (int nn = 0; nn < 4; nn++) {
    f32x4 accr = (f32x4){0.f, 0.f, 0.f, 0.f};
    int cn = cnt[nn];
    int j = 0;
    for (; j + 4 <= cn; j += 4) {
      int   s0 = __shfl(sj[nn], j + 0, 32); float q0 = __shfl(pj[nn], j + 0, 32);
      int   s1 = __shfl(sj[nn], j + 1, 32); float q1 = __shfl(pj[nn], j + 1, 32);
      int   s2 = __shfl(sj[nn], j + 2, 32); float q2 = __shfl(pj[nn], j + 2, 32);
      int   s3 = __shfl(sj[nn], j + 3, 32); float q3 = __shfl(pj[nn], j + 3, 32);
      u32x2 g0 = ((const u32x2*)(x_bf + (size_t)s0 * DIM))[l];
      u32x2 g1 = ((const u32x2*)(x_bf + (size_t)s1 * DIM))[l];
      u32x2 g2 = ((const u32x2*)(x_bf + (size_t)s2 * DIM))[l];
      u32x2 g3 = ((const u32x2*)(x_bf + (size_t)s3 * DIM))[l];
      accr.x += q0*bflo(g0.x) + q1*bflo(g1.x) + q2*bflo(g2.x) + q3*bflo(g3.x);
      accr.y += q0*bfhi(g0.x) + q1*bfhi(g1.x) + q2*bfhi(g2.x) + q3*bfhi(g3.x);
      accr.z += q0*bflo(g0.y) + q1*bflo(g1.y) + q2*bflo(g2.y) + q3*bflo(g3.y);
      accr.w += q0*bfhi(g0.y) + q1*bfhi(g1.y) + q2*bfhi(g2.y) + q3*bfhi(g3.y);
    }
    for (; j < cn; j++) {
      int   s0 = __shfl(sj[nn], j, 32); float q0 = __shfl(pj[nn], j, 32);
      u32x2 g0 = ((const u32x2*)(x_bf + (size_t)s0 * DIM))[l];
      accr.x += q0*bflo(g0.x); accr.y += q0*bfhi(g0.x);
      accr.z += q0*bflo(g0.y); accr.w += q0*bfhi(g0.y);
    }
    f32x4 agg;
    agg.x = accr.x * dinv[nn];
    agg.y = accr.y * dinv[nn];
    agg.z = accr.z * dinv[nn];
    agg.w = accr.w * dinv[nn];
    agg.x += __shfl_xor(agg.x, 32, 64);   // combine rel0 + rel1 halves
    agg.y += __shfl_xor(agg.y, 32, 64);
    agg.z += __shfl_xor(agg.z, 32, 64);
    agg.w += __shfl_xor(agg.w, 32, 64);
    if (wl < 32) {
      const float* gr = &gtile[w * 4 + nn][4 * wl];
      f32x4 o;
      o.x = gr[0] + agg.x; o.y = gr[1] + agg.y;
      o.z = gr[2] + agg.z; o.w = gr[3] + agg.w;
      __builtin_nontemporal_store(o, (f32x4*)(out + (size_t)(nbase + nn) * DIM) + wl);
    }
  }
  __syncthreads();   // gtile reused next iteration
}

// ---------------------------------------------------------------------------
// Cooperative mega-kernel: 1 dispatch, 2 grid syncs, round-1 phase code.
// ---------------------------------------------------------------------------
__global__ __launch_bounds__(256) void mega_kernel(
    const float* __restrict__ x, const float* __restrict__ attn_w,
    const float* __restrict__ W, const float* __restrict__ bias,
    const int* __restrict__ src, const int* __restrict__ dst,
    float* __restrict__ pexp, int* __restrict__ counts, int* __restrict__ slots,
    unsigned short* __restrict__ Wt, unsigned short* __restrict__ x_bf,
    float* __restrict__ out) {
  __shared__ float gtile[16][GDIM];           // 8448 B -> occupancy VGPR-limited
  int tid  = threadIdx.x;
  int gtid = blockIdx.x * 256 + tid;
  int gsz  = gridDim.x * 256;
  do_wtconv(Wt, W, gtid, gsz);
  do_zero(counts, gtid, gsz);
  cg::this_grid().sync();
  do_bin(src, dst, counts, slots, gtid, gsz);             // atomics issue early...
  do_scores(x, attn_w, pexp, x_bf, gtid >> 6, gsz >> 6, tid & 63);  // ...hide under BW
  cg::this_grid().sync();
  for (int tb = blockIdx.x; tb < ROW_TILES; tb += gridDim.x)
    do_tile(gtile, slots, counts, pexp, x_bf, Wt, bias, out, tid, tb);
}

// ---------------------------------------------------------------------------
// Fallback: exact round-1 3-dispatch structure (insurance, known 227.7 us).
// ---------------------------------------------------------------------------
#define FB_WCONV_BLOCKS 8
#define FB_BIN_BLOCKS ((N_EDGES + 255) / 256)                 // 1172
#define FB_ZERO_BLOCKS ((NBINS * CNT_STRIDE / 4 + 255) / 256) // 1563
#define FB_SCORE_BLOCKS (N_NODES / 4)                         // 25000

__global__ __launch_bounds__(256) void fb_k0(int* __restrict__ counts,
                                             unsigned short* __restrict__ Wt,
                                             const float* __restrict__ W) {
  if (blockIdx.x < FB_WCONV_BLOCKS) {
    do_wtconv(Wt, W, blockIdx.x * 256 + threadIdx.x, FB_WCONV_BLOCKS * 256);
    return;
  }
  do_zero(counts, (blockIdx.x - FB_WCONV_BLOCKS) * 256 + threadIdx.x,
          FB_ZERO_BLOCKS * 256);
}
__global__ __launch_bounds__(256) void fb_k1(
    const float* __restrict__ x, const float* __restrict__ attn_w,
    const int* __restrict__ src, const int* __restrict__ dst,
    float* __restrict__ pexp, int* __restrict__ counts, int* __restrict__ slots,
    unsigned short* __restrict__ x_bf) {
  if (blockIdx.x < FB_BIN_BLOCKS) {
    do_bin(src, dst, counts, slots, blockIdx.x * 256 + threadIdx.x, FB_BIN_BLOCKS * 256);
    return;
  }
  int wave = ((blockIdx.x - FB_BIN_BLOCKS) * 256 + (int)threadIdx.x) >> 6;
  do_scores(x, attn_w, pexp, x_bf, wave, N_NODES, threadIdx.x & 63);  // one-shot
}
__global__ __launch_bounds__(256) void fb_k2(
    const int* __restrict__ slots, const int* __restrict__ counts,
    const float* __restrict__ pexp, const unsigned short* __restrict__ x_bf,
    const unsigned short* __restrict__ Wt, const float* __restrict__ bias,
    float* __restrict__ out) {
  __shared__ float gtile[16][GDIM];
  do_tile(gtile, slots, counts, pexp, x_bf, Wt, bias, out, threadIdx.x, blockIdx.x);
}

extern "C" void kernel_launch(void* const* d_in, const int* in_sizes, int n_in,
                              void* d_out, int out_size, void* d_ws, size_t ws_size,
                              hipStream_t stream) {
  const float* x      = (const float*)d_in[0];
  const float* attn_w = (const float*)d_in[1];
  const float* loop_w = (const float*)d_in[2];
  const float* h_bias = (const float*)d_in[3];
  const int*   src    = (const int*)d_in[4];
  const int*   dst    = (const int*)d_in[5];
  float*       out    = (float*)d_out;

  // ws: pexp[2N] f (0.8MB) | counts[2N*8] i (6.4MB) | slots[2N*24] i (19.2MB) |
  //     Wt[128*128] u16 (32KB) | x_bf[N*128] u16 (25.6MB) = 52.03MB (ws >= 54.4MB)
  float*          pexp   = (float*)d_ws;
  int*            counts = (int*)(pexp + NBINS);
  int*            slots  = counts + (size_t)NBINS * CNT_STRIDE;
  unsigned short* Wt     = (unsigned short*)(slots + (size_t)NBINS * SLOT_CAP);
  unsigned short* x_bf   = Wt + DIM * DIM;

  static int coop_blocks = -2;   // -2 untested, -1 fallback, >0 coop grid size
  if (coop_blocks == -2) {
    int bpc = 0;
    hipError_t qe = hipOccupancyMaxActiveBlocksPerMultiprocessor(
        &bpc, (const void*)mega_kernel, 256, 0);
    coop_blocks = (qe == hipSuccess && bpc >= 1) ? bpc * 256 : -1;
  }
  if (coop_blocks > 0) {
    void* args[] = {(void*)&x, (void*)&attn_w, (void*)&loop_w, (void*)&h_bias,
                    (void*)&src, (void*)&dst, (void*)&pexp, (void*)&counts,
                    (void*)&slots, (void*)&Wt, (void*)&x_bf, (void*)&out};
    hipError_t le = hipLaunchCooperativeKernel((const void*)mega_kernel,
        dim3(coop_blocks), dim3(256), args, 0, stream);
    if (le == hipSuccess) return;
    coop_blocks = -1;            // rejected -> classic path
  }
  fb_k0<<<FB_WCONV_BLOCKS + FB_ZERO_BLOCKS, 256, 0, stream>>>(counts, Wt, loop_w);
  fb_k1<<<FB_BIN_BLOCKS + FB_SCORE_BLOCKS, 256, 0, stream>>>(
      x, attn_w, src, dst, pexp, counts, slots, x_bf);
  fb_k2<<<ROW_TILES, 256, 0, stream>>>(slots, counts, pexp, x_bf, Wt, h_bias, out);
}

// Round 4
// 221.668 us; speedup vs baseline: 2.1849x; 1.8726x over previous
//
#include <hip/hip_runtime.h>

#define N_NODES 100000
#define N_EDGES 300000
#define DIM     128
#define NBINS   (2 * N_NODES)        // bin = dst*2 + rel
#define CNT_STRIDE 8                 // 32B per bin (atomic line spreading)
#define SLOT_CAP 24                  // Poisson(3): P(any deg>=24) ~ 5e-9; passed R1-R3
#define ROW_TILES (N_NODES / 16)     // 6250 (16 rows per tile, exact)
#define GDIM (DIM + 4)               // gtile pad: kills 4-way conflict (R3: conflicts=0)

#define WCONV_BLOCKS 8
#define BIN_BLOCKS  ((N_EDGES + 255) / 256)   // 1172
#define SCORE_BLOCKS (N_NODES / 4)            // 25000 (1 wave per node, one-shot)

typedef __attribute__((ext_vector_type(8))) short bfrag;            // 8 bf16
typedef __attribute__((ext_vector_type(4))) float f32x4;
typedef __attribute__((ext_vector_type(2))) float f32x2;
typedef __attribute__((ext_vector_type(2))) unsigned int   u32x2;

__device__ __forceinline__ unsigned short f2bf(float f) {
  unsigned int u = __float_as_uint(f);
  u += 0x7FFFu + ((u >> 16) & 1u);    // round-to-nearest-even
  return (unsigned short)(u >> 16);
}
__device__ __forceinline__ float bflo(unsigned int u) { return __uint_as_float(u << 16); }
__device__ __forceinline__ float bfhi(unsigned int u) { return __uint_as_float(u & 0xffff0000u); }

// ---------------------------------------------------------------------------
// K1: [W -> bf16 W^T (global; L2-resident for K2)] + [edge binning] +
//     [node scores -> pexp, x -> x_bf]   (disjoint block ranges).
// ALGEBRA: dst-side attention term is constant per softmax segment and
// cancels in alpha; only exp(sS[src]) matters.
// ---------------------------------------------------------------------------
__global__ __launch_bounds__(256) void k1_kernel(
    const float* __restrict__ x, const float* __restrict__ attn_w,
    const float* __restrict__ W,
    const int* __restrict__ src, const int* __restrict__ dst,
    float* __restrict__ pexp, int* __restrict__ counts, int* __restrict__ slots,
    unsigned short* __restrict__ Wt, unsigned short* __restrict__ x_bf) {
  if (blockIdx.x < WCONV_BLOCKS) {
    for (int e = blockIdx.x * 256 + threadIdx.x; e < DIM * DIM; e += WCONV_BLOCKS * 256) {
      int k = e >> 7, c = e & 127;
      Wt[c * DIM + k] = f2bf(W[e]);
    }
    return;
  }
  if (blockIdx.x < WCONV_BLOCKS + BIN_BLOCKS) {
    int e = (blockIdx.x - WCONV_BLOCKS) * 256 + threadIdx.x;
    if (e < N_EDGES) {
      int d0 = __builtin_nontemporal_load(&dst[e]);
      int d1 = __builtin_nontemporal_load(&dst[e + N_EDGES]);
      int s0 = __builtin_nontemporal_load(&src[e]);
      int s1 = __builtin_nontemporal_load(&src[e + N_EDGES]);
      int p0 = atomicAdd(&counts[(size_t)(d0 * 2 + 0) * CNT_STRIDE], 1);   // 2 indep chains
      int p1 = atomicAdd(&counts[(size_t)(d1 * 2 + 1) * CNT_STRIDE], 1);
      if (p0 < SLOT_CAP)
        __builtin_nontemporal_store(s0, &slots[(size_t)(d0 * 2 + 0) * SLOT_CAP + p0]);
      if (p1 < SLOT_CAP)
        __builtin_nontemporal_store(s1, &slots[(size_t)(d1 * 2 + 1) * SLOT_CAP + p1]);
    }
    return;
  }
  // ---- scores: one wave per node; 64 lanes x f32x2 = coalesced 512B row read.
  int wave = (((blockIdx.x - WCONV_BLOCKS - BIN_BLOCKS) * 256) + (int)threadIdx.x) >> 6;
  int lane = threadIdx.x & 63;
  if (wave >= N_NODES) return;
  f32x2 a0 = ((const f32x2*)(attn_w +   0))[lane];   // rel0 src-half
  f32x2 a1 = ((const f32x2*)(attn_w + 256))[lane];   // rel1 src-half
  f32x2 v = __builtin_nontemporal_load(((const f32x2*)(x + (size_t)wave * DIM)) + lane);
  ushort2 bv; bv.x = f2bf(v.x); bv.y = f2bf(v.y);
  ((ushort2*)(x_bf + (size_t)wave * DIM))[lane] = bv;
  float p0 = v.x * a0.x + v.y * a0.y;
  float p1 = v.x * a1.x + v.y * a1.y;
  #pragma unroll
  for (int off = 32; off > 0; off >>= 1) {
    p0 += __shfl_down(p0, off, 64);
    p1 += __shfl_down(p1, off, 64);
  }
  if (lane == 0) {
    pexp[wave]           = __expf(p0);
    pexp[N_NODES + wave] = __expf(p1);
  }
}

// ---------------------------------------------------------------------------
// K2: fused [MFMA GEMM x@W + bias -> padded LDS] + [attention aggregate].
// One block per 16-row tile. Aggregate issues 16 unconditional row-gathers
// (4 nodes x 4-deep) before any FMA: lanes past cnt were masked to sj=0 so
// excess gathers hit row 0 (one hot L1 line) and their qv=0 FMAs are no-ops.
// In-flight bytes/wave: 1KB -> 4KB. No launch-bounds min-waves: the R2 spill
// disaster was the (256,4) VGPR cap, not the batch itself.
// ---------------------------------------------------------------------------
__global__ __launch_bounds__(256) void k2_kernel(
    const int* __restrict__ slots, const int* __restrict__ counts,
    const float* __restrict__ pexp, const unsigned short* __restrict__ x_bf,
    const unsigned short* __restrict__ Wt, const float* __restrict__ bias,
    float* __restrict__ out) {
  __shared__ float gtile[16][GDIM];
  int tid = threadIdx.x;
  int r0  = blockIdx.x * 16;
  int w   = tid >> 6;
  int wl  = tid & 63;
  {
    // GEMM quarter: wave w owns column-tiles {2w,2w+1}; C/D layout
    // col = ct*16 + (lane&15), row = (lane>>4)*4 + rr. Bias in acc init.
    int n = wl & 15, q = wl >> 4;
    const unsigned short* xrow = x_bf + (size_t)(r0 + n) * DIM;
    f32x4 acc[2];
    #pragma unroll
    for (int c = 0; c < 2; c++) {
      float bv = bias[(2 * w + c) * 16 + n];
      acc[c] = (f32x4){bv, bv, bv, bv};
    }
    #pragma unroll
    for (int kc = 0; kc < 4; kc++) {
      int k0 = kc * 32 + q * 8;
      bfrag a = *((const bfrag*)(xrow + k0));
      #pragma unroll
      for (int c = 0; c < 2; c++) {
        bfrag b = *((const bfrag*)(Wt + (size_t)((2 * w + c) * 16 + n) * DIM + k0));
        acc[c] = __builtin_amdgcn_mfma_f32_16x16x32_bf16(a, b, acc[c], 0, 0, 0);
      }
    }
    #pragma unroll
    for (int c = 0; c < 2; c++)
      #pragma unroll
      for (int rr = 0; rr < 4; rr++)
        gtile[q * 4 + rr][(2 * w + c) * 16 + n] = acc[c][rr];
  }
  __syncthreads();
  // ---- aggregation: half-wave rrel handles relation rrel; 4 nodes/wave.
  int rrel  = wl >> 5;
  int l     = wl & 31;
  int nbase = r0 + w * 4;
  int craw[4], sraw[4];
  #pragma unroll
  for (int nn = 0; nn < 4; nn++)
    craw[nn] = counts[(size_t)((nbase + nn) * 2 + rrel) * CNT_STRIDE];
  #pragma unroll
  for (int nn = 0; nn < 4; nn++)   // independent of craw: 8 loads in flight
    sraw[nn] = slots[(size_t)((nbase + nn) * 2 + rrel) * SLOT_CAP + l];
  int cnt[4]; int sj[4];
  #pragma unroll
  for (int nn = 0; nn < 4; nn++) {
    cnt[nn] = (craw[nn] > SLOT_CAP) ? SLOT_CAP : craw[nn];
    sj[nn]  = (l < cnt[nn]) ? sraw[nn] : 0;    // mask garbage -> row 0 (valid)
  }
  float pl[4];
  #pragma unroll
  for (int nn = 0; nn < 4; nn++)   // unconditional: 4 loads in flight
    pl[nn] = pexp[rrel * N_NODES + sj[nn]];
  float pj[4]; float dinv[4];
  #pragma unroll
  for (int nn = 0; nn < 4; nn++) {
    pj[nn] = (l < cnt[nn]) ? pl[nn] : 0.f;
    float d = pj[nn];
    #pragma unroll
    for (int off = 16; off > 0; off >>= 1) d += __shfl_xor(d, off, 64);  // in-half
    dinv[nn] = (cnt[nn] > 0) ? 1.f / d : 0.f;
  }
  // Batch-ISSUE: 16 unconditional row-gathers (4KB/wave in flight), zero waits.
  u32x2 g[4][4];
  #pragma unroll
  for (int u = 0; u < 4; u++) {
    #pragma unroll
    for (int nn = 0; nn < 4; nn++) {
      int s = __shfl(sj[nn], u, 32);           // u>=cnt -> s=0 -> hot L1 line
      g[nn][u] = ((const u32x2*)(x_bf + (size_t)s * DIM))[l];
    }
  }
  // FMA phase (qv=0 for u>=cnt -> no-op adds).
  f32x4 accr[4];
  #pragma unroll
  for (int nn = 0; nn < 4; nn++) accr[nn] = (f32x4){0.f, 0.f, 0.f, 0.f};
  #pragma unroll
  for (int nn = 0; nn < 4; nn++) {
    #pragma unroll
    for (int u = 0; u < 4; u++) {
      float qv = __shfl(pj[nn], u, 32);
      u32x2 gv = g[nn][u];
      accr[nn].x += qv * bflo(gv.x);
      accr[nn].y += qv * bfhi(gv.x);
      accr[nn].z += qv * bflo(gv.y);
      accr[nn].w += qv * bfhi(gv.y);
    }
  }
  // Tail for cnt > 4 (P(cnt>4 | Poisson 3) ~ 18% of bins): 4-wide batches.
  #pragma unroll
  for (int nn = 0; nn < 4; nn++) {
    int cn = cnt[nn];
    int j = 4;
    for (; j + 4 <= cn; j += 4) {
      int   s0 = __shfl(sj[nn], j + 0, 32); float q0 = __shfl(pj[nn], j + 0, 32);
      int   s1 = __shfl(sj[nn], j + 1, 32); float q1 = __shfl(pj[nn], j + 1, 32);
      int   s2 = __shfl(sj[nn], j + 2, 32); float q2 = __shfl(pj[nn], j + 2, 32);
      int   s3 = __shfl(sj[nn], j + 3, 32); float q3 = __shfl(pj[nn], j + 3, 32);
      u32x2 g0 = ((const u32x2*)(x_bf + (size_t)s0 * DIM))[l];
      u32x2 g1 = ((const u32x2*)(x_bf + (size_t)s1 * DIM))[l];
      u32x2 g2 = ((const u32x2*)(x_bf + (size_t)s2 * DIM))[l];
      u32x2 g3 = ((const u32x2*)(x_bf + (size_t)s3 * DIM))[l];
      accr[nn].x += q0*bflo(g0.x) + q1*bflo(g1.x) + q2*bflo(g2.x) + q3*bflo(g3.x);
      accr[nn].y += q0*bfhi(g0.x) + q1*bfhi(g1.x) + q2*bfhi(g2.x) + q3*bfhi(g3.x);
      accr[nn].z += q0*bflo(g0.y) + q1*bflo(g1.y) + q2*bflo(g2.y) + q3*bflo(g3.y);
      accr[nn].w += q0*bfhi(g0.y) + q1*bfhi(g1.y) + q2*bfhi(g2.y) + q3*bfhi(g3.y);
    }
    for (; j < cn; j++) {
      int   s0 = __shfl(sj[nn], j, 32); float q0 = __shfl(pj[nn], j, 32);
      u32x2 g0 = ((const u32x2*)(x_bf + (size_t)s0 * DIM))[l];
      accr[nn].x += q0*bflo(g0.x); accr[nn].y += q0*bfhi(g0.x);
      accr[nn].z += q0*bflo(g0.y); accr[nn].w += q0*bfhi(g0.y);
    }
  }
  #pragma unroll
  for (int nn = 0; nn < 4; nn++) {
    f32x4 agg;
    agg.x = accr[nn].x * dinv[nn];
    agg.y = accr[nn].y * dinv[nn];
    agg.z = accr[nn].z * dinv[nn];
    agg.w = accr[nn].w * dinv[nn];
    agg.x += __shfl_xor(agg.x, 32, 64);   // combine rel0 + rel1 halves
    agg.y += __shfl_xor(agg.y, 32, 64);
    agg.z += __shfl_xor(agg.z, 32, 64);
    agg.w += __shfl_xor(agg.w, 32, 64);
    if (wl < 32) {
      const float* gr = &gtile[w * 4 + nn][4 * wl];
      f32x4 o;
      o.x = gr[0] + agg.x; o.y = gr[1] + agg.y;
      o.z = gr[2] + agg.z; o.w = gr[3] + agg.w;
      __builtin_nontemporal_store(o, (f32x4*)(out + (size_t)(r0 + w * 4 + nn) * DIM) + wl);
    }
  }
}

extern "C" void kernel_launch(void* const* d_in, const int* in_sizes, int n_in,
                              void* d_out, int out_size, void* d_ws, size_t ws_size,
                              hipStream_t stream) {
  const float* x      = (const float*)d_in[0];
  const float* attn_w = (const float*)d_in[1];
  const float* loop_w = (const float*)d_in[2];
  const float* h_bias = (const float*)d_in[3];
  const int*   src    = (const int*)d_in[4];
  const int*   dst    = (const int*)d_in[5];
  float*       out    = (float*)d_out;

  // ws: pexp[2N] f (0.8MB) | counts[2N*8] i (6.4MB) | slots[2N*24] i (19.2MB) |
  //     Wt[128*128] u16 (32KB) | x_bf[N*128] u16 (25.6MB) = 52.03MB (ws >= 54.4MB)
  float*          pexp   = (float*)d_ws;
  int*            counts = (int*)(pexp + NBINS);
  int*            slots  = counts + (size_t)NBINS * CNT_STRIDE;
  unsigned short* Wt     = (unsigned short*)(slots + (size_t)NBINS * SLOT_CAP);
  unsigned short* x_bf   = Wt + DIM * DIM;

  // Zero counts via memset node (graph-capturable; saves one kernel dispatch).
  hipMemsetAsync(counts, 0, (size_t)NBINS * CNT_STRIDE * sizeof(int), stream);
  k1_kernel<<<WCONV_BLOCKS + BIN_BLOCKS + SCORE_BLOCKS, 256, 0, stream>>>(
      x, attn_w, loop_w, src, dst, pexp, counts, slots, Wt, x_bf);
  k2_kernel<<<ROW_TILES, 256, 0, stream>>>(
      slots, counts, pexp, x_bf, Wt, h_bias, out);
}